// Round 9
// baseline (243.289 us; speedup 1.0000x reference)
//
#include <hip/hip_runtime.h>
#include <hip/hip_bf16.h>

#define Tt 512
#define Bb 512
#define DV 256
#define DQ 128
#define DH 64
#define CTXN (Tt * DV)  // 131072 floats: context part of d_out
#define TW 64           // t-rows per block (4 waves x 16)
#define BCH 4           // b's per block (sequential per wave)
#define NCH (Bb / BCH)  // 128 chunks

typedef __attribute__((ext_vector_type(8))) short bf16x8;
typedef __attribute__((ext_vector_type(4))) float f32x4;

__device__ __forceinline__ unsigned short f2bf(float x) {
  unsigned u = __float_as_uint(x);
  u += 0x7FFFu + ((u >> 16) & 1u);   // RNE
  return (unsigned short)(u >> 16);
}

// ---- Kernel 0: prep. blocks 0..511: qh[b,h]; blocks 512..575: W1 -> bf16 ----
__global__ void prep_kernel(const float* __restrict__ query,
                            const float* __restrict__ W1,
                            const float* __restrict__ W2,
                            const float* __restrict__ b1,
                            const float* __restrict__ b2,
                            float* __restrict__ qh,
                            unsigned short* __restrict__ w1bf) {
  __shared__ float q[DQ];
  const int blk = blockIdx.x;
  const int h = threadIdx.x;     // 64
  if (blk < Bb) {
    q[h]      = query[blk * DQ + h];
    q[h + 64] = query[blk * DQ + h + 64];
    __syncthreads();
    const float* w2r = W2 + h * DQ;
    float acc = 0.f;
#pragma unroll 8
    for (int k = 0; k < DQ; ++k) acc = fmaf(w2r[k], q[k], acc);
    qh[blk * DH + h] = acc + b1[h] + b2[h];
  } else {
    int base = (blk - Bb) * 256;
#pragma unroll
    for (int k = 0; k < 4; ++k) {
      int i = base + (k << 6) + h;
      w1bf[i] = f2bf(W1[i]);
    }
  }
}

// ---- Kernel 1: FUSED single HBM pass, barrier-free main loop ----
// grid 1024 = (t-window 0..7) x (chunk 0..127). Block 256 thr = 4 waves ->
// 12-16 waves/CU (vs fused3's 8: the latency fix). Wave wv owns t-rows
// t0+wv*16..+15 for BCH=4 b's sequentially. Per b: GEMM -> tanh -> Wv-dot ->
// e^s (no max: |s| <= sum|Wv|+|bv| <= 8.125), broadcast, accumulate
// num/den in PRIVATE regs (disjoint ownership -> no barrier/atomics).
__global__ __launch_bounds__(256, 3) void fused4_kernel(
    const float* __restrict__ values,
    const unsigned short* __restrict__ w1bf,
    const float* __restrict__ qh,
    const float* __restrict__ Wv,
    const float* __restrict__ bv,
    float* __restrict__ es,       // [Bb][Tt]
    float* __restrict__ num_p,    // [NCH][Tt][DV]
    float* __restrict__ den_p) {  // [Tt][NCH]  (transposed for fin reads)
  __shared__ __align__(16) unsigned short lB[DH * DV];  // 32 KB swizzled W1
  __shared__ float lQh[BCH * DH];                       // 1 KB
  const int tid = threadIdx.x;
  const int chunk = blockIdx.x & (NCH - 1);
  const int t0 = (blockIdx.x >> 7) * TW;
  const int b0 = chunk * BCH;

  // stage W1 bf16 -> lB, XOR-swizzle byte ^= (row&7)<<4
  const uint4* w1v = (const uint4*)w1bf;
#pragma unroll
  for (int i = 0; i < 8; ++i) {
    int vec = i * 256 + tid;
    uint4 d = w1v[vec];
    int row = vec >> 5;
    int u = vec & 31;
    int byte = (row << 9) + (u << 4);
    *(uint4*)((char*)lB + (byte ^ ((row & 7) << 4))) = d;
  }
  lQh[tid] = qh[b0 * DH + tid];   // 256 = BCH*DH exactly
  __syncthreads();

  const int wv = tid >> 6, lane = tid & 63;
  const int lrow = lane & 15, g = lane >> 4;
  const int arow = wv * 16 + lrow;      // wave-local t-row (fixed across b)

  float wvc[4];
#pragma unroll
  for (int nt = 0; nt < 4; ++nt) wvc[nt] = Wv[nt * 16 + lrow];
  const float bv0 = bv[0];

  float num[8][8];   // [ks][e] : v = ks*32 + g*8 + e  (lane-private, 64 VGPR)
#pragma unroll
  for (int ks = 0; ks < 8; ++ks)
#pragma unroll
    for (int e = 0; e < 8; ++e) num[ks][e] = 0.f;
  float den = 0.f;

#pragma unroll 1
  for (int bi = 0; bi < BCH; ++bi) {
    const int b = b0 + bi;
    const float* ap = values + ((size_t)b * Tt + t0 + arow) * DV + g * 8;

    // GEMM: A fragments transient per ks (no big register state)
    f32x4 acc[4];
#pragma unroll
    for (int nt = 0; nt < 4; ++nt) acc[nt] = (f32x4){0.f, 0.f, 0.f, 0.f};
#pragma unroll
    for (int ks = 0; ks < 8; ++ks) {
      float4 f0 = *(const float4*)(ap + ks * 32);
      float4 f1 = *(const float4*)(ap + ks * 32 + 4);
      bf16x8 af;
      af[0] = (short)f2bf(f0.x); af[1] = (short)f2bf(f0.y);
      af[2] = (short)f2bf(f0.z); af[3] = (short)f2bf(f0.w);
      af[4] = (short)f2bf(f1.x); af[5] = (short)f2bf(f1.y);
      af[6] = (short)f2bf(f1.z); af[7] = (short)f2bf(f1.w);
      int k2 = (ks * 32 + g * 8) * 2;
#pragma unroll
      for (int nt = 0; nt < 4; ++nt) {
        int brow = nt * 16 + lrow;
        bf16x8 bf = *(const bf16x8*)((const char*)lB +
                                     (((brow << 9) + k2) ^ ((brow & 7) << 4)));
        acc[nt] = __builtin_amdgcn_mfma_f32_16x16x32_bf16(af, bf, acc[nt], 0, 0, 0);
      }
    }

    // epilogue: +qh, tanh (rcp form: shorter chain), *Wv, 16-lane reduce
    const float* qrow = lQh + bi * DH;
    float sc[4] = {0.f, 0.f, 0.f, 0.f};
#pragma unroll
    for (int nt = 0; nt < 4; ++nt) {
      float qv = qrow[nt * 16 + lrow];
#pragma unroll
      for (int j = 0; j < 4; ++j) {
        float hv = acc[nt][j] + qv;
        float e2 = __expf(2.f * hv);
        float th = 1.f - 2.f * __builtin_amdgcn_rcpf(e2 + 1.f);
        sc[j] = fmaf(th, wvc[nt], sc[j]);
      }
    }
#pragma unroll
    for (int j = 0; j < 4; ++j) {
      float v = sc[j];
      v += __shfl_xor(v, 1);
      v += __shfl_xor(v, 2);
      v += __shfl_xor(v, 4);
      v += __shfl_xor(v, 8);
      sc[j] = __expf(v + bv0);   // e^s for wave-local row g*4+j
    }
    if (lrow == 0) {
#pragma unroll
      for (int j = 0; j < 4; ++j)
        es[(size_t)b * Tt + t0 + wv * 16 + g * 4 + j] = sc[j];
    }
    // broadcast: lane's own row (lrow) is held at lane (lrow>>2)*16, reg lrow&3
    int src = (lrow >> 2) << 4;
    float w0 = __shfl(sc[0], src), w1 = __shfl(sc[1], src);
    float w2 = __shfl(sc[2], src), w3 = __shfl(sc[3], src);
    int jm = lrow & 3;
    float w = (jm == 0) ? w0 : (jm == 1) ? w1 : (jm == 2) ? w2 : w3;
    den += w;
    // accumulate num += w * v (f32 re-read, L1/L2-hot, loads independent of w)
#pragma unroll
    for (int ks = 0; ks < 8; ++ks) {
      float4 v0 = *(const float4*)(ap + ks * 32);
      float4 v1 = *(const float4*)(ap + ks * 32 + 4);
      num[ks][0] = fmaf(w, v0.x, num[ks][0]);
      num[ks][1] = fmaf(w, v0.y, num[ks][1]);
      num[ks][2] = fmaf(w, v0.z, num[ks][2]);
      num[ks][3] = fmaf(w, v0.w, num[ks][3]);
      num[ks][4] = fmaf(w, v1.x, num[ks][4]);
      num[ks][5] = fmaf(w, v1.y, num[ks][5]);
      num[ks][6] = fmaf(w, v1.z, num[ks][6]);
      num[ks][7] = fmaf(w, v1.w, num[ks][7]);
    }
  }

  // write partials
  float* np = num_p + ((size_t)chunk * Tt + t0 + arow) * DV + g * 8;
#pragma unroll
  for (int ks = 0; ks < 8; ++ks) {
    *(float4*)(np + ks * 32) =
        make_float4(num[ks][0], num[ks][1], num[ks][2], num[ks][3]);
    *(float4*)(np + ks * 32 + 4) =
        make_float4(num[ks][4], num[ks][5], num[ks][6], num[ks][7]);
  }
  if (g == 0) den_p[(t0 + arow) * NCH + chunk] = den;
}

// ---- Kernel 2: merged finalize. blocks 0..511: context[t]; 512..1023: weights[b].
// Weight-blocks recompute Z from den_p (256 KB, L2-hot) -- no cross-block dep.
__global__ __launch_bounds__(256) void fin_kernel(
    const float* __restrict__ num_p, const float* __restrict__ den_p,
    const float* __restrict__ es, float* __restrict__ out) {
  const int blk = blockIdx.x;
  const int tid = threadIdx.x;
  if (blk < Tt) {
    const int t = blk;
    float Z = 0.f;
    const float4* dp = (const float4*)(den_p + t * NCH);
#pragma unroll
    for (int i = 0; i < NCH / 4; ++i) {
      float4 d = dp[i];
      Z += (d.x + d.y) + (d.z + d.w);
    }
    float s = 0.f;
#pragma unroll 8
    for (int c = 0; c < NCH; ++c)
      s += num_p[((size_t)c * Tt + t) * DV + tid];
    out[t * DV + tid] = s / Z;
  } else {
    const int b = blk - Tt;
#pragma unroll
    for (int i = 0; i < 2; ++i) {
      const int t = i * 256 + tid;
      float Z = 0.f;
      const float4* dp = (const float4*)(den_p + t * NCH);
#pragma unroll
      for (int k = 0; k < NCH / 4; ++k) {
        float4 d = dp[k];
        Z += (d.x + d.y) + (d.z + d.w);
      }
      out[CTXN + b * Tt + t] = es[(size_t)b * Tt + t] / Z;
    }
  }
}

extern "C" void kernel_launch(void* const* d_in, const int* in_sizes, int n_in,
                              void* d_out, int out_size, void* d_ws, size_t ws_size,
                              hipStream_t stream) {
  const float* query  = (const float*)d_in[0];
  const float* values = (const float*)d_in[1];
  const float* W1     = (const float*)d_in[2];
  const float* b1     = (const float*)d_in[3];
  const float* W2     = (const float*)d_in[4];
  const float* b2     = (const float*)d_in[5];
  const float* Wv     = (const float*)d_in[6];
  const float* bv     = (const float*)d_in[7];
  float* out = (float*)d_out;
  char* ws = (char*)d_ws;
  float* qh            = (float*)ws;                       // 128 KiB
  unsigned short* w1bf = (unsigned short*)(ws + 131072);   //  32 KiB
  float* es            = (float*)(ws + 163840);            //   1 MiB
  float* den_p         = (float*)(ws + 1212416);           // 256 KiB
  float* num_p         = (float*)(ws + (size_t)2 * 1024 * 1024);  // 64 MiB

  prep_kernel<<<dim3(Bb + 64), dim3(64), 0, stream>>>(query, W1, W2, b1, b2, qh, w1bf);
  fused4_kernel<<<dim3(1024), dim3(256), 0, stream>>>(values, w1bf, qh, Wv, bv,
                                                      es, num_p, den_p);
  fin_kernel<<<dim3(1024), dim3(256), 0, stream>>>(num_p, den_p, es, out);
}

// Round 10
// 95.456 us; speedup vs baseline: 2.5487x; 2.5487x over previous
//
#include <hip/hip_runtime.h>
#include <hip/hip_bf16.h>

#define Tt 512
#define Bb 512
#define DV 256
#define DQ 128
#define DH 64
#define CTXN (Tt * DV)  // 131072 floats: context part of d_out

typedef __attribute__((ext_vector_type(8))) short bf16x8;
typedef __attribute__((ext_vector_type(4))) float f32x4;

__device__ __forceinline__ unsigned short f2bf(float x) {
  unsigned u = __float_as_uint(x);
  u += 0x7FFFu + ((u >> 16) & 1u);   // RNE
  return (unsigned short)(u >> 16);
}

// ---- Kernel 0: prep. blocks 0..511: qh[b,h]; blocks 512..575: W1 -> bf16 ----
__global__ void prep_kernel(const float* __restrict__ query,
                            const float* __restrict__ W1,
                            const float* __restrict__ W2,
                            const float* __restrict__ b1,
                            const float* __restrict__ b2,
                            float* __restrict__ qh,
                            unsigned short* __restrict__ w1bf) {
  __shared__ float q[DQ];
  const int blk = blockIdx.x;
  const int h = threadIdx.x;     // 64
  if (blk < Bb) {
    q[h]      = query[blk * DQ + h];
    q[h + 64] = query[blk * DQ + h + 64];
    __syncthreads();
    const float* w2r = W2 + h * DQ;
    float acc = 0.f;
#pragma unroll 8
    for (int k = 0; k < DQ; ++k) acc = fmaf(w2r[k], q[k], acc);
    qh[blk * DH + h] = acc + b1[h] + b2[h];
  } else {
    int base = (blk - Bb) * 256;
#pragma unroll
    for (int k = 0; k < 4; ++k) {
      int i = base + (k << 6) + h;
      w1bf[i] = f2bf(W1[i]);
    }
  }
}

// ---- Kernel 1: scores -> e^s. Round-3 structure (proven ~5+ TB/s). ----
// Block = 64 rows (one b, 64 consecutive t). A direct global->reg->bf16 (no
// reuse); B (W1) in swizzled LDS. No max subtraction: |s| <= sum|Wv|+|bv|
// <= 8.125 -> e^s <= 3383 (f32-safe, validated rounds 5-9).
// esT[t*512 + b] = e^s.
__global__ __launch_bounds__(256, 4) void score_kernel(
    const float* __restrict__ values,
    const unsigned short* __restrict__ w1bf,
    const float* __restrict__ qh,
    const float* __restrict__ Wv,
    const float* __restrict__ bv,
    float* __restrict__ esT) {
  __shared__ __align__(16) unsigned short lB[DH * DV];  // 32 KB, swizzled bf16
  const int tid = threadIdx.x;
  const int m0 = blockIdx.x * 64;
  const int bidx = m0 >> 9;       // all 64 rows share the same b (64 | 512)

  // stage W1 bf16 -> lB (16B units), XOR-swizzle byte ^= (row&7)<<4
  const uint4* w1v = (const uint4*)w1bf;
#pragma unroll
  for (int i = 0; i < 8; ++i) {
    int vec = i * 256 + tid;        // 2048 units of 16B
    uint4 d = w1v[vec];
    int row = vec >> 5;             // 32 units per 256-elem row
    int u = vec & 31;
    int byte = (row << 9) + (u << 4);
    *(uint4*)((char*)lB + (byte ^ ((row & 7) << 4))) = d;
  }
  __syncthreads();

  const int wv = tid >> 6;        // wave 0..3 -> A rows 16*wv .. +15
  const int lane = tid & 63;
  const int lrow = lane & 15;
  const int g = lane >> 4;        // k-group

  f32x4 acc[4];
#pragma unroll
  for (int nt = 0; nt < 4; ++nt) acc[nt] = (f32x4){0.f, 0.f, 0.f, 0.f};

  const int arow = wv * 16 + lrow;
  const float* ap = values + (size_t)(m0 + arow) * DV;

#pragma unroll
  for (int ks = 0; ks < 8; ++ks) {
    // lane's A fragment: row arow, elements ks*32 + g*8 .. +7 (f32 -> bf16)
    const float* fp = ap + ks * 32 + g * 8;
    float4 f0 = *(const float4*)(fp);
    float4 f1 = *(const float4*)(fp + 4);
    bf16x8 af;
    af[0] = (short)f2bf(f0.x); af[1] = (short)f2bf(f0.y);
    af[2] = (short)f2bf(f0.z); af[3] = (short)f2bf(f0.w);
    af[4] = (short)f2bf(f1.x); af[5] = (short)f2bf(f1.y);
    af[6] = (short)f2bf(f1.z); af[7] = (short)f2bf(f1.w);
    int k2 = (ks * 32 + g * 8) * 2;  // byte offset of k within a B row
#pragma unroll
    for (int nt = 0; nt < 4; ++nt) {
      int brow = nt * 16 + lrow;
      bf16x8 bf = *(const bf16x8*)((const char*)lB +
                                   (((brow << 9) + k2) ^ ((brow & 7) << 4)));
      acc[nt] = __builtin_amdgcn_mfma_f32_16x16x32_bf16(af, bf, acc[nt], 0, 0, 0);
    }
  }

  // epilogue: h + qh -> tanh -> * Wv, reduce over 64 cols -> e^s
  float bv0 = bv[0];
  float sc[4] = {0.f, 0.f, 0.f, 0.f};
#pragma unroll
  for (int nt = 0; nt < 4; ++nt) {
    int col = nt * 16 + lrow;
    float qv = qh[bidx * DH + col];
    float wvc = Wv[col];
#pragma unroll
    for (int j = 0; j < 4; ++j) {
      float hv = acc[nt][j] + qv;
      float e = __expf(2.f * hv);
      float th = (e - 1.f) / (e + 1.f);
      sc[j] = fmaf(th, wvc, sc[j]);
    }
  }
#pragma unroll
  for (int j = 0; j < 4; ++j) {
    float v = sc[j];
    v += __shfl_xor(v, 1);
    v += __shfl_xor(v, 2);
    v += __shfl_xor(v, 4);
    v += __shfl_xor(v, 8);
    sc[j] = v;
  }
  if (lrow == 0) {
#pragma unroll
    for (int j = 0; j < 4; ++j) {
      int m = m0 + wv * 16 + g * 4 + j;
      int tt = m & (Tt - 1);
      esT[tt * Bb + bidx] = __expf(sc[j] + bv0);   // e^s
    }
  }
}

// ---- Kernel 2: per-t Z + context. b DESCENDING (L3 tail reuse: score just
// streamed values ascending through the 256MB Infinity Cache, so high-b is
// resident). No weight write here (strided scatter moved to fin_w).
__global__ __launch_bounds__(1024, 2) void ctx3_kernel(
    const float* __restrict__ values,
    const float* __restrict__ esT,
    float* __restrict__ invZbuf,
    float* __restrict__ out) {
  const int t = blockIdx.x;
  const int tid = threadIdx.x;
  const int wv = tid >> 6, lane = tid & 63;
  __shared__ float wbuf[Bb];           // e^s (unnormalized)
  __shared__ float ssum[16];
  __shared__ float red[32][DV];        // 32 KB

  float es = (tid < Bb) ? esT[t * Bb + tid] : 0.f;   // contiguous 2 KB
  float zs = es;
#pragma unroll
  for (int d = 1; d < 64; d <<= 1) zs += __shfl_xor(zs, d);
  if (lane == 0) ssum[wv] = zs;
  if (tid < Bb) wbuf[tid] = es;
  __syncthreads();
  float Z = 0.f;
#pragma unroll
  for (int i = 0; i < 16; ++i) Z += ssum[i];
  const float invZ = 1.f / Z;
  if (tid == 0) invZbuf[t] = invZ;

  // context[t,:] = invZ * sum_b e^s[b] * v[b,t,:], b descending
  const int unit = tid & 31;   // 8-elem v-slice
  const int b0 = tid >> 5;     // 0..31
  float av[8] = {0.f, 0.f, 0.f, 0.f, 0.f, 0.f, 0.f, 0.f};
#pragma unroll 4
  for (int i = 0; i < 16; ++i) {
    int b = ((15 - i) << 5) + b0;            // 480+b0, 448+b0, ... 0+b0
    float w = wbuf[b];
    const float* p = values + ((size_t)b * Tt + t) * DV + unit * 8;
    float4 a = ((const float4*)p)[0];
    float4 c = ((const float4*)p)[1];
    av[0] = fmaf(w, a.x, av[0]); av[1] = fmaf(w, a.y, av[1]);
    av[2] = fmaf(w, a.z, av[2]); av[3] = fmaf(w, a.w, av[3]);
    av[4] = fmaf(w, c.x, av[4]); av[5] = fmaf(w, c.y, av[5]);
    av[6] = fmaf(w, c.z, av[6]); av[7] = fmaf(w, c.w, av[7]);
  }
#pragma unroll
  for (int j = 0; j < 8; ++j) red[b0][unit * 8 + j] = av[j];
  __syncthreads();
  if (tid < DV) {
    float tot = 0.f;
#pragma unroll
    for (int b = 0; b < 32; ++b) tot += red[b][tid];
    out[t * DV + tid] = tot * invZ;
  }
}

// ---- Kernel 3: weights[b,t] = e^s[t,b] * invZ[t], via LDS transpose ----
// grid 64 = (t-tile 0..7) x (b-tile 0..7); 64x64 tile; both sides coalesced.
__global__ __launch_bounds__(256) void fin_w_kernel(
    const float* __restrict__ esT, const float* __restrict__ invZbuf,
    float* __restrict__ out) {
  __shared__ float tile[64][65];   // +1 pad: conflict-free transposed read
  const int tid = threadIdx.x;
  const int t0 = (blockIdx.x >> 3) * 64;
  const int b0 = (blockIdx.x & 7) * 64;
  const int rr = tid >> 6;         // 0..3
  const int cc = tid & 63;         // 0..63
#pragma unroll
  for (int k = 0; k < 16; ++k) {
    int r = rr + (k << 2);         // t-local 0..63
    tile[r][cc] = esT[(t0 + r) * Bb + b0 + cc];   // coalesced 256B rows
  }
  const float iz = invZbuf[t0 + cc];   // coalesced, reused across k
  __syncthreads();
#pragma unroll
  for (int k = 0; k < 16; ++k) {
    int br = rr + (k << 2);        // b-local 0..63
    out[CTXN + (size_t)(b0 + br) * Tt + t0 + cc] = tile[cc][br] * iz;
  }
}

extern "C" void kernel_launch(void* const* d_in, const int* in_sizes, int n_in,
                              void* d_out, int out_size, void* d_ws, size_t ws_size,
                              hipStream_t stream) {
  const float* query  = (const float*)d_in[0];
  const float* values = (const float*)d_in[1];
  const float* W1     = (const float*)d_in[2];
  const float* b1     = (const float*)d_in[3];
  const float* W2     = (const float*)d_in[4];
  const float* b2     = (const float*)d_in[5];
  const float* Wv     = (const float*)d_in[6];
  const float* bv     = (const float*)d_in[7];
  float* out = (float*)d_out;
  char* ws = (char*)d_ws;
  float* qh            = (float*)ws;                       // 128 KiB
  unsigned short* w1bf = (unsigned short*)(ws + 131072);   //  32 KiB
  float* esT           = (float*)(ws + 163840);            //   1 MiB
  float* invZbuf       = (float*)(ws + 1212416);           //   2 KiB

  prep_kernel<<<dim3(Bb + 64), dim3(64), 0, stream>>>(query, W1, W2, b1, b2, qh, w1bf);
  score_kernel<<<dim3((Bb * Tt) / 64), dim3(256), 0, stream>>>(
      values, w1bf, qh, Wv, bv, esT);
  ctx3_kernel<<<dim3(Tt), dim3(1024), 0, stream>>>(values, esT, invZbuf, out);
  fin_w_kernel<<<dim3(64), dim3(256), 0, stream>>>(esT, invZbuf, out);
}